// Round 2
// baseline (118.855 us; speedup 1.0000x reference)
//
#include <hip/hip_runtime.h>
#include <hip/hip_bf16.h>

#define HDIM 2048

// ---------------------------------------------------------------------------
// Feature MLP: feat(462) -> fd1(66) -> fd2(66). Tiny; one block.
// ---------------------------------------------------------------------------
__global__ __launch_bounds__(128) void mlp_kernel(
    const float* __restrict__ feat,      // 462
    const float* __restrict__ f1_w,      // (66,462)
    const float* __restrict__ f1_b,      // 66
    const float* __restrict__ f2_w,      // (66,66)
    const float* __restrict__ f2_b,      // 66
    float* __restrict__ fd2_out)         // 66
{
    __shared__ float fd1[66];
    const int t = threadIdx.x;
    if (t < 66) {
        float s = f1_b[t];
        const float* row = f1_w + t * 462;
        for (int k = 0; k < 462; ++k) s = fmaf(row[k], feat[k], s);
        fd1[t] = s;
    }
    __syncthreads();
    if (t < 66) {
        float s = f2_b[t];
        const float* row = f2_w + t * 66;
        for (int k = 0; k < 66; ++k) s = fmaf(row[k], fd1[k], s);
        fd2_out[t] = s;
    }
}

// ---------------------------------------------------------------------------
// hid = h0 @ emb_w.T + emb_b + (fd2 @ f3_w.T + f3_b).  One thread per output.
// ---------------------------------------------------------------------------
__global__ __launch_bounds__(256) void hid_kernel(
    const float* __restrict__ h0,        // 34
    const float* __restrict__ emb_w,     // (H,34)
    const float* __restrict__ emb_b,     // H
    const float* __restrict__ f3_w,      // (H,66)
    const float* __restrict__ f3_b,      // H
    const float* __restrict__ fd2,       // 66
    float* __restrict__ h_out)           // H
{
    const int j = blockIdx.x * blockDim.x + threadIdx.x;
    if (j >= HDIM) return;
    float s = emb_b[j] + f3_b[j];
    const float* er = emb_w + j * 34;
    for (int k = 0; k < 34; ++k) s = fmaf(er[k], h0[k], s);
    const float* fr = f3_w + j * 66;
    for (int k = 0; k < 66; ++k) s = fmaf(fr[k], fd2[k], s);
    h_out[j] = s;
}

// ---------------------------------------------------------------------------
// One GRU step. One 64-lane wave per output element j (2048 waves).
// Each wave: 3 dot products of length H over rows j, H+j, 2H+j of w_hh.
// h vector float4s loaded once per iteration, reused for all 3 rows.
// Coalesced: lanes read consecutive float4s (1 KiB / instruction / wave).
// ---------------------------------------------------------------------------
__global__ __launch_bounds__(256) void gru_step_kernel(
    const float* __restrict__ w_hh,      // (3H,H)   [already offset to step]
    const float* __restrict__ w_ih,      // (3H)     [col 0; already offset]
    const float* __restrict__ b_ih,      // (3H)
    const float* __restrict__ b_hh,      // (3H)
    const float* __restrict__ xt,        // (7)
    const int step,
    const float* __restrict__ h_in,      // H
    float* __restrict__ h_out)           // H
{
    const int wave = (blockIdx.x * blockDim.x + threadIdx.x) >> 6;  // 0..H-1
    const int lane = threadIdx.x & 63;
    const int j = wave;

    const float4* hv4 = (const float4*)h_in;
    const float4* wr  = (const float4*)(w_hh + (size_t)j * HDIM);
    const float4* wz  = (const float4*)(w_hh + (size_t)(HDIM + j) * HDIM);
    const float4* wn  = (const float4*)(w_hh + (size_t)(2 * HDIM + j) * HDIM);

    float sr = 0.f, sz = 0.f, sn = 0.f;
#pragma unroll
    for (int i = 0; i < 8; ++i) {
        const int idx = i * 64 + lane;           // float4 index, 512 per row
        const float4 h4 = hv4[idx];
        const float4 a  = wr[idx];
        const float4 b  = wz[idx];
        const float4 c  = wn[idx];
        sr = fmaf(a.x, h4.x, fmaf(a.y, h4.y, fmaf(a.z, h4.z, fmaf(a.w, h4.w, sr))));
        sz = fmaf(b.x, h4.x, fmaf(b.y, h4.y, fmaf(b.z, h4.z, fmaf(b.w, h4.w, sz))));
        sn = fmaf(c.x, h4.x, fmaf(c.y, h4.y, fmaf(c.z, h4.z, fmaf(c.w, h4.w, sn))));
    }
    // wave (64-lane) reduction
#pragma unroll
    for (int off = 32; off > 0; off >>= 1) {
        sr += __shfl_down(sr, off);
        sz += __shfl_down(sz, off);
        sn += __shfl_down(sn, off);
    }

    if (lane == 0) {
        const float x = xt[step];
        const float gir = fmaf(x, w_ih[j],            b_ih[j]);
        const float giz = fmaf(x, w_ih[HDIM + j],     b_ih[HDIM + j]);
        const float gin = fmaf(x, w_ih[2 * HDIM + j], b_ih[2 * HDIM + j]);
        const float ghr = sr + b_hh[j];
        const float ghz = sz + b_hh[HDIM + j];
        const float ghn = sn + b_hh[2 * HDIM + j];
        const float r = 1.f / (1.f + expf(-(gir + ghr)));
        const float z = 1.f / (1.f + expf(-(giz + ghz)));
        const float n = tanhf(fmaf(r, ghn, gin));
        h_out[j] = fmaf(z, h_in[j] - n, n);   // (1-z)*n + z*h
    }
}

// ---------------------------------------------------------------------------
// out = h7 . out_w[0:H] + restrict*out_w[H] + number*out_w[H+1] + out_b
// Output is FLOAT32 (reference is pure fp32 JAX).
// ---------------------------------------------------------------------------
__global__ __launch_bounds__(256) void out_kernel(
    const float* __restrict__ h7,        // H
    const float* __restrict__ out_w,     // H+2
    const float* __restrict__ out_b,     // 1
    const float* __restrict__ restr,     // 1
    const float* __restrict__ number,    // 1
    float* __restrict__ out)             // 1 (fp32)
{
    __shared__ float red[256];
    const int t = threadIdx.x;
    float s = 0.f;
    for (int k = t; k < HDIM; k += 256) s = fmaf(out_w[k], h7[k], s);
    red[t] = s;
    __syncthreads();
#pragma unroll
    for (int off = 128; off > 0; off >>= 1) {
        if (t < off) red[t] += red[t + off];
        __syncthreads();
    }
    if (t == 0) {
        out[0] = red[0] + restr[0] * out_w[HDIM] + number[0] * out_w[HDIM + 1]
               + out_b[0];
    }
}

// ---------------------------------------------------------------------------
extern "C" void kernel_launch(void* const* d_in, const int* in_sizes, int n_in,
                              void* d_out, int out_size, void* d_ws, size_t ws_size,
                              hipStream_t stream) {
    const float* xt     = (const float*)d_in[0];
    const float* h0     = (const float*)d_in[1];
    const float* feat   = (const float*)d_in[2];
    const float* number = (const float*)d_in[3];
    const float* restr  = (const float*)d_in[4];
    const float* w_ih   = (const float*)d_in[5];
    const float* w_hh   = (const float*)d_in[6];
    const float* b_ih   = (const float*)d_in[7];
    const float* b_hh   = (const float*)d_in[8];
    const float* emb_w  = (const float*)d_in[9];
    const float* emb_b  = (const float*)d_in[10];
    const float* f1_w   = (const float*)d_in[11];
    const float* f1_b   = (const float*)d_in[12];
    const float* f2_w   = (const float*)d_in[13];
    const float* f2_b   = (const float*)d_in[14];
    const float* f3_w   = (const float*)d_in[15];
    const float* f3_b   = (const float*)d_in[16];
    const float* out_w  = (const float*)d_in[17];
    const float* out_b  = (const float*)d_in[18];

    float* ws    = (float*)d_ws;
    float* fd2   = ws;              // 66 floats
    float* hbuf0 = ws + 256;        // H floats
    float* hbuf1 = ws + 256 + HDIM; // H floats

    mlp_kernel<<<1, 128, 0, stream>>>(feat, f1_w, f1_b, f2_w, f2_b, fd2);
    hid_kernel<<<HDIM / 256, 256, 0, stream>>>(h0, emb_w, emb_b, f3_w, f3_b, fd2,
                                               hbuf0);

    float* bufs[2] = {hbuf0, hbuf1};
    for (int s = 0; s < 7; ++s) {
        const float* hin = bufs[s & 1];
        float* hout      = bufs[(s + 1) & 1];
        gru_step_kernel<<<(HDIM * 64) / 256, 256, 0, stream>>>(
            w_hh + (size_t)s * 3 * HDIM * HDIM,
            w_ih + (size_t)s * 3 * HDIM,
            b_ih + (size_t)s * 3 * HDIM,
            b_hh + (size_t)s * 3 * HDIM,
            xt, s, hin, hout);
    }

    out_kernel<<<1, 256, 0, stream>>>(bufs[7 & 1], out_w, out_b, restr, number,
                                      (float*)d_out);
}